// Round 3
// baseline (398.949 us; speedup 1.0000x reference)
//
#include <hip/hip_runtime.h>
#include <math.h>

#define B_  256
#define T_  512
#define D_  256
#define A_  50
#define AP  52      // A padded to multiple of 4 (row stride 208 B, 16B-aligned)
#define EPS 1e-7f

// ---------------------------------------------------------------------------
// Prep: zero-pad W [D,50] -> W_pad [D,52].
// ---------------------------------------------------------------------------
__global__ void pad_w_kernel(const float* __restrict__ W, float* __restrict__ Wp)
{
    int idx = blockIdx.x * 256 + threadIdx.x;
    if (idx >= D_ * AP) return;
    int d = idx / AP;
    int a = idx - d * AP;
    Wp[idx] = (a < A_) ? W[d * A_ + a] : 0.0f;
}

// ---------------------------------------------------------------------------
// Kernel 1: scores, K-split 2-way for occupancy.
// 1024 blocks x 256 threads. Block covers 128 rows; thread (h = tid>>7,
// rl = tid&127) accumulates d in [h*128, h*128+128) for row r. Partners
// combine acc[52] via LDS, then h=0 threads do tanh·u, exp, store, and
// block-reduce the exp-scores into partial[block] (4 blocks per batch).
// W is read with wave-uniform addresses -> scalar K$ loads, no VALU cost.
// ---------------------------------------------------------------------------
__global__ __launch_bounds__(256)
void scores_kernel(const float* __restrict__ x, const float* __restrict__ Wp,
                   const float* __restrict__ bias, const float* __restrict__ u,
                   float* __restrict__ s_out, float* __restrict__ partial)
{
    __shared__ float accL[128 * AP];   // 26.6 KB: h=1 partial accs
    __shared__ float red[128];

    const int tid = threadIdx.x;
    const int h   = tid >> 7;          // d-half (wave-uniform)
    const int rl  = tid & 127;         // local row
    const size_t r = (size_t)blockIdx.x * 128 + rl;

    const float4* __restrict__ xr4 = (const float4*)(x + r * D_) + h * 32;

    float acc[AP];
    #pragma unroll
    for (int a = 0; a < AP; a++) acc[a] = 0.0f;

    float4 cur = xr4[0];
    for (int d4 = 0; d4 < 32; d4++) {
        float4 nxt;
        if (d4 < 31) nxt = xr4[d4 + 1];
        const float xr[4] = {cur.x, cur.y, cur.z, cur.w};
        #pragma unroll
        for (int j = 0; j < 4; j++) {
            const float4* __restrict__ wrow =
                (const float4*)(Wp + (size_t)(h * 128 + d4 * 4 + j) * AP);
            #pragma unroll
            for (int a4 = 0; a4 < AP / 4; a4++) {
                const float4 w = wrow[a4];   // wave-uniform -> s_load_dwordx4
                acc[4 * a4 + 0] += xr[j] * w.x;
                acc[4 * a4 + 1] += xr[j] * w.y;
                acc[4 * a4 + 2] += xr[j] * w.z;
                acc[4 * a4 + 3] += xr[j] * w.w;
            }
        }
        cur = nxt;
    }

    if (h == 1) {
        #pragma unroll
        for (int a4 = 0; a4 < AP / 4; a4++)
            *(float4*)(&accL[rl * AP + 4 * a4]) =
                make_float4(acc[4*a4+0], acc[4*a4+1], acc[4*a4+2], acc[4*a4+3]);
    }
    __syncthreads();

    if (h == 0) {
        float sc = 0.0f;
        #pragma unroll
        for (int a = 0; a < A_; a++) {
            float v = acc[a] + accL[rl * AP + a] + bias[a];
            sc += tanhf(v) * u[a];
        }
        const float s = expf(sc);
        s_out[r] = s;
        red[rl] = s;
    }
    __syncthreads();

    for (int off = 64; off > 0; off >>= 1) {
        if (tid < off) red[tid] += red[tid + off];
        __syncthreads();
    }
    if (tid == 0) partial[blockIdx.x] = red[0];
}

// ---------------------------------------------------------------------------
// Kernel 2: pool over a t-quarter. 1024 blocks = (batch, quarter).
// Wave w covers 32 t's; lane l owns float4 d-chunk l (64*4 = 256 = D).
// Coalesced 1KB/wave loads. Result per quarter -> pp[(b*4+q)*256 + d].
// ---------------------------------------------------------------------------
__global__ __launch_bounds__(256)
void pool_kernel(const float* __restrict__ x, const float* __restrict__ s_in,
                 const float* __restrict__ partial, float* __restrict__ pp)
{
    __shared__ float s_lds[128];
    __shared__ float part[4 * 256];

    const int tid = threadIdx.x;
    const int bb  = blockIdx.x >> 2;
    const int q   = blockIdx.x & 3;

    const float inv = 1.0f / (partial[4*bb] + partial[4*bb+1] +
                              partial[4*bb+2] + partial[4*bb+3] + EPS);
    if (tid < 128)
        s_lds[tid] = s_in[(size_t)bb * T_ + q * 128 + tid] * inv;
    __syncthreads();

    const int w = tid >> 6;
    const int l = tid & 63;

    const float* __restrict__ xb = x + ((size_t)bb * T_ + q * 128) * D_;
    float4 acc = make_float4(0.f, 0.f, 0.f, 0.f);

    #pragma unroll 4
    for (int i = 0; i < 32; i++) {
        const int t = w * 32 + i;
        float4 xv = *(const float4*)(xb + (size_t)t * D_ + l * 4);
        float sv  = s_lds[t];
        acc.x += xv.x * sv;
        acc.y += xv.y * sv;
        acc.z += xv.z * sv;
        acc.w += xv.w * sv;
    }

    part[w * 256 + l * 4 + 0] = acc.x;
    part[w * 256 + l * 4 + 1] = acc.y;
    part[w * 256 + l * 4 + 2] = acc.z;
    part[w * 256 + l * 4 + 3] = acc.w;
    __syncthreads();

    pp[(size_t)blockIdx.x * 256 + tid] =
        part[tid] + part[256 + tid] + part[512 + tid] + part[768 + tid];
}

// ---------------------------------------------------------------------------
// Kernel 3: combine the 4 t-quarter partials -> out[b,d].
// ---------------------------------------------------------------------------
__global__ __launch_bounds__(256)
void combine_kernel(const float* __restrict__ pp, float* __restrict__ out)
{
    const size_t idx = (size_t)blockIdx.x * 256 + threadIdx.x;  // b*256 + d
    const size_t b   = idx >> 8;
    const size_t d   = idx & 255;
    out[idx] = pp[(b*4+0)*256 + d] + pp[(b*4+1)*256 + d] +
               pp[(b*4+2)*256 + d] + pp[(b*4+3)*256 + d];
}

// ---------------------------------------------------------------------------
extern "C" void kernel_launch(void* const* d_in, const int* in_sizes, int n_in,
                              void* d_out, int out_size, void* d_ws, size_t ws_size,
                              hipStream_t stream)
{
    const float* x = (const float*)d_in[0];
    const float* W = (const float*)d_in[1];
    const float* b = (const float*)d_in[2];
    const float* u = (const float*)d_in[3];

    float* scores  = (float*)d_ws;                       // 131072 floats
    float* partial = scores + (size_t)B_ * T_;           // 1024 floats
    float* Wp      = partial + 1024;                     // 13312 floats
    float* pp      = Wp + (size_t)D_ * AP;               // 262144 floats
    float* out     = (float*)d_out;

    pad_w_kernel   <<<(D_ * AP + 255) / 256, 256, 0, stream>>>(W, Wp);
    scores_kernel  <<<(B_ * T_) / 128, 256, 0, stream>>>(x, Wp, b, u, scores, partial);
    pool_kernel    <<<B_ * 4, 256, 0, stream>>>(x, scores, partial, pp);
    combine_kernel <<<B_, 256, 0, stream>>>(pp, out);
}

// Round 4
// 257.830 us; speedup vs baseline: 1.5473x; 1.5473x over previous
//
#include <hip/hip_runtime.h>
#include <math.h>

#define B_  256
#define T_  512
#define D_  256
#define A_  50
#define AP  52      // A padded to mult of 4 (row stride 208 B, 16B-aligned)
#define APL 53      // LDS stride for acc combine (gcd(53,32)=1 -> no conflicts)
#define EPS 1e-7f

// ---------------------------------------------------------------------------
// Prep: zero-pad W [D,50] -> W_pad [D,52].
// ---------------------------------------------------------------------------
__global__ void pad_w_kernel(const float* __restrict__ W, float* __restrict__ Wp)
{
    int idx = blockIdx.x * 256 + threadIdx.x;
    if (idx >= D_ * AP) return;
    int d = idx / AP;
    int a = idx - d * AP;
    Wp[idx] = (a < A_) ? W[d * A_ + a] : 0.0f;
}

// ---------------------------------------------------------------------------
// Kernel 1: scores, 2-way K-split. 512 blocks x 512 threads (8 waves).
// h = readfirstlane(tid>>8) is forced into an SGPR so the W row address is
// PROVABLY wave-uniform -> s_load through the scalar K$ (this is the whole
// game: R2 lost 2x because h=tid>>7 made these per-lane global_loads).
// Thread (h, rl) accumulates d in [h*128, h*128+128) for row r; halves
// combine via LDS (stride 53 -> conflict-free), h=0 does tanh·u + exp.
// ---------------------------------------------------------------------------
__global__ __launch_bounds__(512)
void scores_kernel(const float* __restrict__ x, const float* __restrict__ Wp,
                   const float* __restrict__ bias, const float* __restrict__ u,
                   float* __restrict__ s_out, float* __restrict__ partial)
{
    __shared__ float accL[256 * APL];   // 54.3 KB
    __shared__ float red[256];

    const int tid = threadIdx.x;
    const int h   = __builtin_amdgcn_readfirstlane(tid >> 8);  // 0/1, SGPR
    const int rl  = tid & 255;
    const size_t r = (size_t)blockIdx.x * 256 + rl;

    const float4* __restrict__ xr4 = (const float4*)(x + r * D_) + h * 32;
    const float*  __restrict__ Wh  = Wp + (size_t)h * 128 * AP;  // scalar base

    float acc[AP];
    #pragma unroll
    for (int a = 0; a < AP; a++) acc[a] = 0.0f;

    for (int d4 = 0; d4 < 32; d4++) {
        const float4 xv = xr4[d4];
        const float xr[4] = {xv.x, xv.y, xv.z, xv.w};
        #pragma unroll
        for (int j = 0; j < 4; j++) {
            const float4* __restrict__ wrow =
                (const float4*)(Wh + (size_t)(d4 * 4 + j) * AP);
            #pragma unroll
            for (int a4 = 0; a4 < AP / 4; a4++) {
                const float4 w = wrow[a4];   // uniform -> s_load_dwordx4
                acc[4 * a4 + 0] += xr[j] * w.x;
                acc[4 * a4 + 1] += xr[j] * w.y;
                acc[4 * a4 + 2] += xr[j] * w.z;
                acc[4 * a4 + 3] += xr[j] * w.w;
            }
        }
    }

    if (h == 1) {
        #pragma unroll
        for (int a = 0; a < AP; a++) accL[rl * APL + a] = acc[a];
    }
    __syncthreads();

    if (h == 0) {
        float sc = 0.0f;
        #pragma unroll
        for (int a = 0; a < A_; a++) {
            float v = acc[a] + accL[rl * APL + a] + bias[a];
            sc += tanhf(v) * u[a];
        }
        const float s = expf(sc);
        s_out[r] = s;
        red[rl] = s;
    }
    __syncthreads();

    for (int off = 128; off > 0; off >>= 1) {
        if (tid < off) red[tid] += red[tid + off];
        __syncthreads();
    }
    if (tid == 0) partial[blockIdx.x] = red[0];  // 512 partials, 2 per batch
}

// ---------------------------------------------------------------------------
// Kernel 2: pool over a t-chunk of 64. 2048 blocks = (batch, chunk q of 8)
// -> 8 blocks/CU (32 waves/CU). Wave w covers 16 t's, fully unrolled so all
// 16 loads are independent and in flight; lane l owns float4 d-chunk l
// (64*4 = 256 = D) -> perfectly coalesced 1KB/wave loads.
// ---------------------------------------------------------------------------
__global__ __launch_bounds__(256)
void pool_kernel(const float* __restrict__ x, const float* __restrict__ s_in,
                 const float* __restrict__ partial, float* __restrict__ pp)
{
    __shared__ float s_lds[64];
    __shared__ float part[4 * 256];

    const int tid = threadIdx.x;
    const int bb  = blockIdx.x >> 3;
    const int q   = blockIdx.x & 7;

    const float inv = 1.0f / (partial[2 * bb] + partial[2 * bb + 1] + EPS);
    if (tid < 64)
        s_lds[tid] = s_in[(size_t)bb * T_ + q * 64 + tid] * inv;
    __syncthreads();

    const int w = tid >> 6;
    const int l = tid & 63;

    const float* __restrict__ xb = x + ((size_t)bb * T_ + q * 64) * D_;
    float4 acc = make_float4(0.f, 0.f, 0.f, 0.f);

    #pragma unroll
    for (int i = 0; i < 16; i++) {
        const int t = w * 16 + i;
        float4 xv = *(const float4*)(xb + (size_t)t * D_ + l * 4);
        float sv  = s_lds[t];
        acc.x += xv.x * sv;
        acc.y += xv.y * sv;
        acc.z += xv.z * sv;
        acc.w += xv.w * sv;
    }

    part[w * 256 + l * 4 + 0] = acc.x;
    part[w * 256 + l * 4 + 1] = acc.y;
    part[w * 256 + l * 4 + 2] = acc.z;
    part[w * 256 + l * 4 + 3] = acc.w;
    __syncthreads();

    pp[(size_t)blockIdx.x * 256 + tid] =
        part[tid] + part[256 + tid] + part[512 + tid] + part[768 + tid];
}

// ---------------------------------------------------------------------------
// Kernel 3: combine the 8 t-chunk partials -> out[b,d].
// ---------------------------------------------------------------------------
__global__ __launch_bounds__(256)
void combine_kernel(const float* __restrict__ pp, float* __restrict__ out)
{
    const size_t idx = (size_t)blockIdx.x * 256 + threadIdx.x;  // b*256 + d
    const size_t b   = idx >> 8;
    const size_t d   = idx & 255;
    float o = 0.0f;
    #pragma unroll
    for (int q = 0; q < 8; q++) o += pp[(b * 8 + q) * 256 + d];
    out[idx] = o;
}

// ---------------------------------------------------------------------------
extern "C" void kernel_launch(void* const* d_in, const int* in_sizes, int n_in,
                              void* d_out, int out_size, void* d_ws, size_t ws_size,
                              hipStream_t stream)
{
    const float* x = (const float*)d_in[0];
    const float* W = (const float*)d_in[1];
    const float* b = (const float*)d_in[2];
    const float* u = (const float*)d_in[3];

    float* scores  = (float*)d_ws;                       // 131072 floats
    float* partial = scores + (size_t)B_ * T_;           // 512 floats
    float* Wp      = partial + 512;                      // 13312 floats
    float* pp      = Wp + (size_t)D_ * AP;               // 524288 floats
    float* out     = (float*)d_out;

    pad_w_kernel   <<<(D_ * AP + 255) / 256, 256, 0, stream>>>(W, Wp);
    scores_kernel  <<<(B_ * T_) / 256, 512, 0, stream>>>(x, Wp, b, u, scores, partial);
    pool_kernel    <<<B_ * 8, 256, 0, stream>>>(x, scores, partial, pp);
    combine_kernel <<<B_, 256, 0, stream>>>(pp, out);
}

// Round 6
// 224.431 us; speedup vs baseline: 1.7776x; 1.1488x over previous
//
#include <hip/hip_runtime.h>
#include <math.h>

#define B_  256
#define T_  512
#define D_  256
#define A_  50
#define EPS 1e-7f

typedef short  short8  __attribute__((ext_vector_type(8)));
typedef float  floatx4 __attribute__((ext_vector_type(4)));

__device__ inline unsigned short f2bf(float f) {
    unsigned int u = __float_as_uint(f);
    u = (u + 0x7fffu + ((u >> 16) & 1u)) >> 16;   // RNE (inputs are finite)
    return (unsigned short)u;
}

// ---------------------------------------------------------------------------
// Prep: swizzle W [256][50] fp32 into bf16 B-fragment order for
// mfma_f32_16x16x32_bf16, zero-padded to N=64. Fragment (nt,ks), lane l,
// element j holds B[k][n] with n = nt*16 + (l&15), k = ks*32 + (l>>4)*8 + j.
// Layout: Wf[((nt*8+ks)*64 + l)*8 + j]. Also emits bias/u zero-padded to 64
// (u pad = 0 kills the fake columns in the epilogue dot).
// ---------------------------------------------------------------------------
__global__ void prep_kernel(const float* __restrict__ W,
                            const float* __restrict__ bias,
                            const float* __restrict__ u,
                            unsigned short* __restrict__ Wf,
                            float* __restrict__ bu64)
{
    int idx = blockIdx.x * 256 + threadIdx.x;      // 0 .. 16383
    int j  = idx & 7;
    int l  = (idx >> 3) & 63;
    int ks = (idx >> 9) & 7;
    int nt = idx >> 12;
    int n  = nt * 16 + (l & 15);
    int k  = ks * 32 + (l >> 4) * 8 + j;
    float val = (n < A_) ? W[k * A_ + n] : 0.0f;
    Wf[idx] = f2bf(val);
    if (idx < 64) {
        bu64[idx]      = (idx < A_) ? bias[idx] : 0.0f;
        bu64[64 + idx] = (idx < A_) ? u[idx]    : 0.0f;
    }
}

// ---------------------------------------------------------------------------
// Kernel 1: scores via MFMA. 2048 blocks x 256 threads; wave w owns rows
// [blk*64 + w*16, +16). A-frags come straight from global x (lane = row
// c=l&15, k-slice quad*8: two float4 loads = 32B contiguous; adjacent lanes
// cover full 64B lines) converted to bf16 in-register. B-frags are per-lane
// 16B loads from pre-swizzled Wf (L2-resident). K-loop: 8 ks x 4 nt MFMAs.
// Epilogue: C layout col=l&15,row=quad*4+r (m89-verified); tanh(.+b)*u,
// width-16 shfl_xor butterfly sums over n, exp, store + block partial.
// ---------------------------------------------------------------------------
__global__ __launch_bounds__(256)
void scores_kernel(const float* __restrict__ x,
                   const unsigned short* __restrict__ Wf,
                   const float* __restrict__ bu64,
                   float* __restrict__ s_out, float* __restrict__ partial)
{
    __shared__ float sred[64];

    const int tid  = threadIdx.x;
    const int w    = tid >> 6;
    const int l    = tid & 63;
    const int c    = l & 15;        // A-row / C-col within tile
    const int quad = l >> 4;        // k-slice / C-row-group
    const size_t rowbase = (size_t)blockIdx.x * 64 + w * 16;

    const float4* __restrict__ xrow = (const float4*)(x + (rowbase + c) * D_);
    const short8* __restrict__ wf8  = (const short8*)Wf;

    float bnc[4], unc[4];
    #pragma unroll
    for (int nt = 0; nt < 4; nt++) {
        bnc[nt] = bu64[nt * 16 + c];
        unc[nt] = bu64[64 + nt * 16 + c];
    }

    floatx4 acc[4];
    #pragma unroll
    for (int nt = 0; nt < 4; nt++) acc[nt] = (floatx4){0.f, 0.f, 0.f, 0.f};

    #pragma unroll
    for (int ks = 0; ks < 8; ks++) {
        const float4 a0 = xrow[ks * 8 + quad * 2];
        const float4 a1 = xrow[ks * 8 + quad * 2 + 1];
        short8 av;
        av[0] = (short)f2bf(a0.x); av[1] = (short)f2bf(a0.y);
        av[2] = (short)f2bf(a0.z); av[3] = (short)f2bf(a0.w);
        av[4] = (short)f2bf(a1.x); av[5] = (short)f2bf(a1.y);
        av[6] = (short)f2bf(a1.z); av[7] = (short)f2bf(a1.w);
        #pragma unroll
        for (int nt = 0; nt < 4; nt++) {
            const short8 bv = wf8[(nt * 8 + ks) * 64 + l];
            acc[nt] = __builtin_amdgcn_mfma_f32_16x16x32_bf16(av, bv, acc[nt], 0, 0, 0);
        }
    }

    // Epilogue: per reg r, this lane holds uit[rowbase+quad*4+r][nt*16+c]
    float part[4];
    #pragma unroll
    for (int r = 0; r < 4; r++) {
        float v = 0.0f;
        #pragma unroll
        for (int nt = 0; nt < 4; nt++)
            v += tanhf(acc[nt][r] + bnc[nt]) * unc[nt];
        #pragma unroll
        for (int off = 1; off < 16; off <<= 1)
            v += __shfl_xor(v, off, 16);
        part[r] = v;
    }

    if (c == 0) {
        #pragma unroll
        for (int r = 0; r < 4; r++) {
            const float s = expf(part[r]);
            s_out[rowbase + quad * 4 + r] = s;
            sred[w * 16 + quad * 4 + r] = s;
        }
    }
    __syncthreads();
    if (tid == 0) {
        float s = 0.0f;
        #pragma unroll
        for (int i = 0; i < 64; i++) s += sred[i];
        partial[blockIdx.x] = s;   // one partial per 64 rows (8 per batch)
    }
}

// ---------------------------------------------------------------------------
// Kernel 2: pool over a t-chunk of 64. 2048 blocks = (batch, chunk q of 8).
// Wave w covers 16 t's fully unrolled (16 independent 1KB coalesced loads);
// lane l owns float4 d-chunk l. Partials -> pp.
// ---------------------------------------------------------------------------
__global__ __launch_bounds__(256)
void pool_kernel(const float* __restrict__ x, const float* __restrict__ s_in,
                 const float* __restrict__ partial, float* __restrict__ pp)
{
    __shared__ float s_lds[64];
    __shared__ float part[4 * 256];

    const int tid = threadIdx.x;
    const int bb  = blockIdx.x >> 3;
    const int q   = blockIdx.x & 7;

    float den = EPS;
    #pragma unroll
    for (int i = 0; i < 8; i++) den += partial[bb * 8 + i];
    const float inv = 1.0f / den;

    if (tid < 64)
        s_lds[tid] = s_in[(size_t)bb * T_ + q * 64 + tid] * inv;
    __syncthreads();

    const int w = tid >> 6;
    const int l = tid & 63;

    const float* __restrict__ xb = x + ((size_t)bb * T_ + q * 64) * D_;
    float4 acc = make_float4(0.f, 0.f, 0.f, 0.f);

    #pragma unroll
    for (int i = 0; i < 16; i++) {
        const int t = w * 16 + i;
        float4 xv = *(const float4*)(xb + (size_t)t * D_ + l * 4);
        float sv  = s_lds[t];
        acc.x += xv.x * sv;
        acc.y += xv.y * sv;
        acc.z += xv.z * sv;
        acc.w += xv.w * sv;
    }

    part[w * 256 + l * 4 + 0] = acc.x;
    part[w * 256 + l * 4 + 1] = acc.y;
    part[w * 256 + l * 4 + 2] = acc.z;
    part[w * 256 + l * 4 + 3] = acc.w;
    __syncthreads();

    pp[(size_t)blockIdx.x * 256 + tid] =
        part[tid] + part[256 + tid] + part[512 + tid] + part[768 + tid];
}

// ---------------------------------------------------------------------------
// Kernel 3: combine the 8 t-chunk partials -> out[b,d].
// ---------------------------------------------------------------------------
__global__ __launch_bounds__(256)
void combine_kernel(const float* __restrict__ pp, float* __restrict__ out)
{
    const size_t idx = (size_t)blockIdx.x * 256 + threadIdx.x;  // b*256 + d
    const size_t b   = idx >> 8;
    const size_t d   = idx & 255;
    float o = 0.0f;
    #pragma unroll
    for (int q = 0; q < 8; q++) o += pp[(b * 8 + q) * 256 + d];
    out[idx] = o;
}

// ---------------------------------------------------------------------------
extern "C" void kernel_launch(void* const* d_in, const int* in_sizes, int n_in,
                              void* d_out, int out_size, void* d_ws, size_t ws_size,
                              hipStream_t stream)
{
    const float* x = (const float*)d_in[0];
    const float* W = (const float*)d_in[1];
    const float* b = (const float*)d_in[2];
    const float* u = (const float*)d_in[3];

    float* scores  = (float*)d_ws;                        // 131072 f
    float* partial = scores + (size_t)B_ * T_;            // 2048 f
    float* bu64    = partial + 2048;                      // 128 f
    float* pp      = bu64 + 128;                          // 524288 f
    unsigned short* Wf = (unsigned short*)(pp + (size_t)B_ * 8 * 256); // 16384 u16
    float* out     = (float*)d_out;

    prep_kernel   <<<64,   256, 0, stream>>>(W, b, u, Wf, bu64);
    scores_kernel <<<2048, 256, 0, stream>>>(x, Wf, bu64, scores, partial);
    pool_kernel   <<<2048, 256, 0, stream>>>(x, scores, partial, pp);
    combine_kernel<<<B_,   256, 0, stream>>>(pp, out);
}

// Round 7
// 219.225 us; speedup vs baseline: 1.8198x; 1.0237x over previous
//
#include <hip/hip_runtime.h>
#include <math.h>

#define B_  256
#define T_  512
#define D_  256
#define A_  50
#define EPS 1e-7f
#define NW  16   // waves per block

typedef short  short8  __attribute__((ext_vector_type(8)));
typedef float  floatx4 __attribute__((ext_vector_type(4)));

__device__ inline unsigned short f2bf(float f) {
    unsigned int u = __float_as_uint(f);
    u = (u + 0x7fffu + ((u >> 16) & 1u)) >> 16;   // RNE (inputs are finite)
    return (unsigned short)u;
}

// ---------------------------------------------------------------------------
// Prep: swizzle W [256][50] fp32 into bf16 B-fragment order for
// mfma_f32_16x16x32_bf16, zero-padded to N=64. Fragment (nt,ks), lane l,
// element j holds B[k][n] with n = nt*16 + (l&15), k = ks*32 + (l>>4)*8 + j.
// Layout: Wf[((nt*8+ks)*64 + l)*8 + j]. Also bias/u zero-padded to 64
// (u pad = 0 kills the fake columns in the epilogue dot).
// ---------------------------------------------------------------------------
__global__ void prep_kernel(const float* __restrict__ W,
                            const float* __restrict__ bias,
                            const float* __restrict__ u,
                            unsigned short* __restrict__ Wf,
                            float* __restrict__ bu64)
{
    int idx = blockIdx.x * 256 + threadIdx.x;      // 0 .. 16383
    int j  = idx & 7;
    int l  = (idx >> 3) & 63;
    int ks = (idx >> 9) & 7;
    int nt = idx >> 12;
    int n  = nt * 16 + (l & 15);
    int k  = ks * 32 + (l >> 4) * 8 + j;
    float val = (n < A_) ? W[k * A_ + n] : 0.0f;
    Wf[idx] = f2bf(val);
    if (idx < 64) {
        bu64[idx]      = (idx < A_) ? bias[idx] : 0.0f;
        bu64[64 + idx] = (idx < A_) ? u[idx]    : 0.0f;
    }
}

// ---------------------------------------------------------------------------
// Fused kernel: one block per batch (256 blocks x 1024 threads, 16 waves).
// Phase 1 (MFMA scores, m89-verified C layout col=l&15,row=quad*4+r):
//   wave w, pass p owns rows p*256 + w*16 .. +16; A-frags straight from
//   global x (32B/lane contiguous), B-frags per-lane 16B from pre-swizzled
//   Wf (L1/L2-resident). Epilogue tanh(.+b)*u, width-16 shfl butterfly,
//   exp -> LDS only (no global round trip).
// Sum: LDS tree over 512 scores -> inv.
// Phase 2: wave w pools t in [w*32, w*32+32): 1KB coalesced loads of x_b
//   (L3-hit: just streamed in phase 1, 134 MB < 256 MB L3), scale by inv,
//   cross-wave combine in LDS, 256 threads write out[b,:].
// ---------------------------------------------------------------------------
__global__ __launch_bounds__(1024)
void fused_kernel(const float* __restrict__ x,
                  const unsigned short* __restrict__ Wf,
                  const float* __restrict__ bu64,
                  float* __restrict__ out)
{
    __shared__ float s_lds[T_];
    __shared__ float part[NW * 256];   // 16 KB (also reduction scratch)

    const int tid  = threadIdx.x;
    const int w    = tid >> 6;
    const int l    = tid & 63;
    const int c    = l & 15;        // A-row / C-col within tile
    const int quad = l >> 4;        // k-slice / C-row-group
    const int bb   = blockIdx.x;

    const float*  __restrict__ xb  = x + (size_t)bb * T_ * D_;
    const short8* __restrict__ wf8 = (const short8*)Wf;

    float bnc[4], unc[4];
    #pragma unroll
    for (int nt = 0; nt < 4; nt++) {
        bnc[nt] = bu64[nt * 16 + c];
        unc[nt] = bu64[64 + nt * 16 + c];
    }

    // ---- Phase 1: scores ----
    #pragma unroll
    for (int pass = 0; pass < 2; pass++) {
        const int rowbase = pass * 256 + w * 16;
        const float4* __restrict__ xrow =
            (const float4*)(xb + (size_t)(rowbase + c) * D_);

        floatx4 acc[4];
        #pragma unroll
        for (int nt = 0; nt < 4; nt++) acc[nt] = (floatx4){0.f, 0.f, 0.f, 0.f};

        #pragma unroll
        for (int ks = 0; ks < 8; ks++) {
            const float4 a0 = xrow[ks * 8 + quad * 2];
            const float4 a1 = xrow[ks * 8 + quad * 2 + 1];
            short8 av;
            av[0] = (short)f2bf(a0.x); av[1] = (short)f2bf(a0.y);
            av[2] = (short)f2bf(a0.z); av[3] = (short)f2bf(a0.w);
            av[4] = (short)f2bf(a1.x); av[5] = (short)f2bf(a1.y);
            av[6] = (short)f2bf(a1.z); av[7] = (short)f2bf(a1.w);
            #pragma unroll
            for (int nt = 0; nt < 4; nt++) {
                const short8 bv = wf8[(nt * 8 + ks) * 64 + l];
                acc[nt] = __builtin_amdgcn_mfma_f32_16x16x32_bf16(av, bv, acc[nt], 0, 0, 0);
            }
        }

        #pragma unroll
        for (int r = 0; r < 4; r++) {
            float v = 0.0f;
            #pragma unroll
            for (int nt = 0; nt < 4; nt++)
                v += tanhf(acc[nt][r] + bnc[nt]) * unc[nt];
            #pragma unroll
            for (int off = 1; off < 16; off <<= 1)
                v += __shfl_xor(v, off, 16);
            if (c == 0)
                s_lds[rowbase + quad * 4 + r] = expf(v);
        }
    }
    __syncthreads();

    // ---- Sum of exp-scores -> inv (LDS tree in part[]) ----
    if (tid < 512) part[tid] = s_lds[tid];
    __syncthreads();
    for (int off = 256; off > 0; off >>= 1) {
        if (tid < off) part[tid] += part[tid + off];
        __syncthreads();
    }
    const float inv = 1.0f / (part[0] + EPS);
    __syncthreads();   // everyone has read part[0] before part is reused

    // ---- Phase 2: weighted pool (x_b re-read is L3-hot) ----
    float4 acc2 = make_float4(0.f, 0.f, 0.f, 0.f);
    const int t0 = w * 32;
    #pragma unroll
    for (int i = 0; i < 32; i++) {
        const float4 xv = *(const float4*)(xb + (size_t)(t0 + i) * D_ + l * 4);
        const float sv  = s_lds[t0 + i];   // wave-uniform -> LDS broadcast
        acc2.x += xv.x * sv;
        acc2.y += xv.y * sv;
        acc2.z += xv.z * sv;
        acc2.w += xv.w * sv;
    }
    acc2.x *= inv; acc2.y *= inv; acc2.z *= inv; acc2.w *= inv;

    part[w * 256 + l * 4 + 0] = acc2.x;
    part[w * 256 + l * 4 + 1] = acc2.y;
    part[w * 256 + l * 4 + 2] = acc2.z;
    part[w * 256 + l * 4 + 3] = acc2.w;
    __syncthreads();

    if (tid < 256) {
        float o = 0.0f;
        #pragma unroll
        for (int wv = 0; wv < NW; wv++) o += part[wv * 256 + tid];
        out[(size_t)bb * 256 + tid] = o;
    }
}

// ---------------------------------------------------------------------------
extern "C" void kernel_launch(void* const* d_in, const int* in_sizes, int n_in,
                              void* d_out, int out_size, void* d_ws, size_t ws_size,
                              hipStream_t stream)
{
    const float* x = (const float*)d_in[0];
    const float* W = (const float*)d_in[1];
    const float* b = (const float*)d_in[2];
    const float* u = (const float*)d_in[3];

    unsigned short* Wf  = (unsigned short*)d_ws;          // 16384 u16
    float*         bu64 = (float*)(Wf + 16384);           // 128 f
    float*         out  = (float*)d_out;

    prep_kernel  <<<64,  256,  0, stream>>>(W, b, u, Wf, bu64);
    fused_kernel <<<B_,  1024, 0, stream>>>(x, Wf, bu64, out);
}